// Round 1
// baseline (288.704 us; speedup 1.0000x reference)
//
#include <hip/hip_runtime.h>

#define VNUM 6890
#define SLEN 20670      // V*3
#define NJ 24
#define NJR 19
#define NB 10
#define NP 207
#define NROWS 219       // 1 (vt) + 10 (shapedirs) + 207 (posedirs) + 1 (ones)
#define NCOLS 480       // 456 (j*24+i, jr*w) + 24 (J_regressor)
#define RL 1440         // NCOLS*3

__constant__ int c_PAR[24]  = {0,0,0,0,1,2,3,4,5,6,7,8,9,9,9,12,13,14,16,17,18,19,20,21};
__constant__ int c_LOFF[10] = {0,1,4,7,10,15,18,20,22,24};

// ---------------------------------------------------------------------------
// Kernel P: CCX[r][col*3+c] = sum_v coef[v,col] * s_r[3v+c]
//   rows r: 0 = v_template, 1..10 = shapedirs, 11..217 = posedirs, 218 = ones
//   cols:   0..455 -> jr[v, col/24] * w[v, col%24];  456..479 -> Jreg[v, col-456]
// Grid: 7 row-tiles(32) x 8 col-tiles(64) x 8 K-splits = 448 blocks, 256 thr.
// Each thread: 2 rows x 4 cols x 3 c = 24 accumulators; atomicAdd at end.
// ---------------------------------------------------------------------------
extern "C" __global__ __launch_bounds__(256) void smpl_pre(
    const float* __restrict__ vt,
    const float* __restrict__ sd,
    const float* __restrict__ pd,
    const float* __restrict__ Jreg,
    const float* __restrict__ jr,
    const float* __restrict__ w,
    float* __restrict__ CCX)
{
    __shared__ float sPl[3][64][34];   // [c][v_local][row_local], pad 34 for float2 reads
    __shared__ float Gl[64][68];       // [v_local][col_local], pad 68 keeps 16B align

    const int bid = blockIdx.x;
    const int ks = bid & 7;
    const int ct = (bid >> 3) & 7;
    const int rt = bid >> 6;           // 0..6
    const int r0 = rt * 32;
    const int c0 = ct * 64;
    const int t  = threadIdx.x;
    const int tc = t & 15;             // -> 4 cols
    const int tr = t >> 4;             // -> 2 rows

    float acc[24];
    #pragma unroll
    for (int u = 0; u < 24; ++u) acc[u] = 0.f;

    int ch0 = ks * 14;                 // chunks of 64 v's; 108 chunks total
    int ch1 = ch0 + 14; if (ch1 > 108) ch1 = 108;

    for (int ch = ch0; ch < ch1; ++ch) {
        const int v0 = ch * 64;
        __syncthreads();               // protect previous iteration's reads

        // ---- stage s rows (de-interleave 3v+c -> [c][v][r]) ----
        for (int idx = t; idx < 32 * 96; idx += 256) {
            const int rl = idx / 96;           // row local 0..31
            const int h  = idx - rl * 96;      // float2 index within row chunk
            const int r  = r0 + rl;
            const int epos = 2 * h;            // element offset inside chunk (0..190)
            const int e = 3 * v0 + epos;       // global element within row
            float f0 = 0.f, f1 = 0.f;
            if (r < NROWS && e < SLEN) {
                if (r == 218) { f0 = 1.f; f1 = 1.f; }
                else {
                    const float* src = (r == 0) ? vt
                                     : (r <= 10 ? sd + (size_t)(r - 1) * SLEN
                                                : pd + (size_t)(r - 11) * SLEN);
                    float2 v2 = *reinterpret_cast<const float2*>(src + e);
                    f0 = v2.x; f1 = v2.y;
                }
            }
            const int va = epos / 3,     ca = epos - va * 3;
            const int vb = (epos+1) / 3, cb = (epos+1) - vb * 3;
            sPl[ca][va][rl] = f0;
            sPl[cb][vb][rl] = f1;
        }

        // ---- build coef tile G ----
        for (int g = t; g < 64 * 64; g += 256) {
            const int vL = g >> 6, colL = g & 63;
            const int colg = c0 + colL;
            const int vg = v0 + vL;
            float val = 0.f;
            if (colg < NCOLS && vg < VNUM) {
                if (colg < 456) {
                    const int j = colg / 24;
                    const int i = colg - j * 24;
                    val = jr[vg * NJR + j] * w[vg * NJ + i];
                } else {
                    val = Jreg[vg * NJ + (colg - 456)];
                }
            }
            Gl[vL][colL] = val;
        }
        __syncthreads();

        // ---- accumulate ----
        #pragma unroll 4
        for (int vL = 0; vL < 64; ++vL) {
            const float4 g = *reinterpret_cast<const float4*>(&Gl[vL][4 * tc]);
            const float2 s0 = *reinterpret_cast<const float2*>(&sPl[0][vL][2 * tr]);
            const float2 s1 = *reinterpret_cast<const float2*>(&sPl[1][vL][2 * tr]);
            const float2 s2 = *reinterpret_cast<const float2*>(&sPl[2][vL][2 * tr]);
            acc[0]  += s0.x * g.x; acc[1]  += s1.x * g.x; acc[2]  += s2.x * g.x;
            acc[3]  += s0.x * g.y; acc[4]  += s1.x * g.y; acc[5]  += s2.x * g.y;
            acc[6]  += s0.x * g.z; acc[7]  += s1.x * g.z; acc[8]  += s2.x * g.z;
            acc[9]  += s0.x * g.w; acc[10] += s1.x * g.w; acc[11] += s2.x * g.w;
            acc[12] += s0.y * g.x; acc[13] += s1.y * g.x; acc[14] += s2.y * g.x;
            acc[15] += s0.y * g.y; acc[16] += s1.y * g.y; acc[17] += s2.y * g.y;
            acc[18] += s0.y * g.z; acc[19] += s1.y * g.z; acc[20] += s2.y * g.z;
            acc[21] += s0.y * g.w; acc[22] += s1.y * g.w; acc[23] += s2.y * g.w;
        }
    }

    #pragma unroll
    for (int dr = 0; dr < 2; ++dr) {
        const int r = r0 + 2 * tr + dr;
        if (r >= NROWS) continue;
        #pragma unroll
        for (int dc = 0; dc < 4; ++dc) {
            const int colg = c0 + 4 * tc + dc;
            if (colg >= NCOLS) continue;
            #pragma unroll
            for (int c = 0; c < 3; ++c)
                atomicAdd(&CCX[(size_t)r * RL + colg * 3 + c], acc[(dr * 4 + dc) * 3 + c]);
        }
    }
}

// ---------------------------------------------------------------------------
// Kernel B: one block per batch item.
//  rodrigues -> x vector; J via CCX cols 456..479; kinematic chain (9 levels);
//  A; M = x @ CCX (1368 outs); joints epilogue (57 outs).
// ---------------------------------------------------------------------------
extern "C" __global__ __launch_bounds__(256) void smpl_batch(
    const float* __restrict__ beta,
    const float* __restrict__ theta,
    const float* __restrict__ CCX,
    float* __restrict__ out)
{
    __shared__ float xs[218];
    __shared__ float Rl[24][9];
    __shared__ float Rg[24][9];
    __shared__ float tg[24][3];
    __shared__ float tA[24][3];
    __shared__ float Jl[24][3];
    __shared__ float Ml[1368];

    const int b = blockIdx.x;
    const int t = threadIdx.x;

    // ---- phase 0/1: rodrigues + x vector ----
    if (t < 24) {
        const int i = t;
        const float tx = theta[b * 72 + 3 * i + 0];
        const float ty = theta[b * 72 + 3 * i + 1];
        const float tz = theta[b * 72 + 3 * i + 2];
        const float ax = tx + 1e-8f, ay = ty + 1e-8f, az = tz + 1e-8f;
        const float angle = sqrtf(ax * ax + ay * ay + az * az);
        const float half = 0.5f * angle;
        const float sh = sinf(half), chh = cosf(half);
        const float inv = 1.f / angle;
        float qw = chh, qx = sh * tx * inv, qy = sh * ty * inv, qz = sh * tz * inv;
        const float rn = 1.f / sqrtf(qw * qw + qx * qx + qy * qy + qz * qz);
        qw *= rn; qx *= rn; qy *= rn; qz *= rn;
        float R[9];
        R[0] = 1.f - 2.f * (qy * qy + qz * qz);
        R[1] = 2.f * (qx * qy - qw * qz);
        R[2] = 2.f * (qx * qz + qw * qy);
        R[3] = 2.f * (qx * qy + qw * qz);
        R[4] = 1.f - 2.f * (qx * qx + qz * qz);
        R[5] = 2.f * (qy * qz - qw * qx);
        R[6] = 2.f * (qx * qz - qw * qy);
        R[7] = 2.f * (qy * qz + qw * qx);
        R[8] = 1.f - 2.f * (qx * qx + qy * qy);
        #pragma unroll
        for (int e = 0; e < 9; ++e) Rl[i][e] = R[e];
        if (i >= 1) {
            #pragma unroll
            for (int e = 0; e < 9; ++e)
                xs[11 + (i - 1) * 9 + e] = R[e] - ((e == 0 || e == 4 || e == 8) ? 1.f : 0.f);
        }
    } else if (t == 24) {
        xs[0] = 1.f;
    } else if (t >= 25 && t < 35) {
        xs[t - 24] = beta[b * NB + (t - 25)];
    }
    __syncthreads();

    // ---- phase 2: J (cols 456..479, rows 0..10) ----
    if (t < 72) {
        const int jj = t / 3, c = t - jj * 3;
        float a = 0.f;
        #pragma unroll
        for (int r = 0; r <= 10; ++r)
            a += xs[r] * CCX[(size_t)r * RL + (456 + jj) * 3 + c];
        Jl[jj][c] = a;
    }
    __syncthreads();

    // ---- phase 3: kinematic chain, 9 topological levels ----
    for (int lv = 0; lv < 9; ++lv) {
        const int beg = c_LOFF[lv];
        const int cnt = c_LOFF[lv + 1] - beg;
        if (t < cnt * 12) {
            const int li = t / 12, e = t - li * 12;
            const int j = beg + li;
            const int r = e >> 2, cc = e & 3;
            if (lv == 0) {
                if (cc < 3) Rg[0][r * 3 + cc] = Rl[0][r * 3 + cc] * ((cc == 0) ? 1.f : -1.f);
                else        tg[0][r] = Jl[0][r];
            } else {
                const int p = c_PAR[j];
                if (cc < 3) {
                    Rg[j][r * 3 + cc] = Rg[p][r * 3 + 0] * Rl[j][0 + cc]
                                      + Rg[p][r * 3 + 1] * Rl[j][3 + cc]
                                      + Rg[p][r * 3 + 2] * Rl[j][6 + cc];
                } else {
                    const float t0 = Jl[j][0] - Jl[p][0];
                    const float t1 = Jl[j][1] - Jl[p][1];
                    const float t2 = Jl[j][2] - Jl[p][2];
                    tg[j][r] = Rg[p][r * 3 + 0] * t0 + Rg[p][r * 3 + 1] * t1
                             + Rg[p][r * 3 + 2] * t2 + tg[p][r];
                }
            }
        }
        __syncthreads();
    }

    // ---- phase 4: A translation ----
    if (t < 72) {
        const int i = t / 3, c = t - (t / 3) * 3;
        tA[i][c] = tg[i][c] - (Rg[i][c * 3 + 0] * Jl[i][0]
                             + Rg[i][c * 3 + 1] * Jl[i][1]
                             + Rg[i][c * 3 + 2] * Jl[i][2]);
    }
    __syncthreads();

    // ---- phase 5: M = x @ CCX (1368 outputs, 6 per thread) ----
    {
        float a0 = 0, a1 = 0, a2 = 0, a3 = 0, a4 = 0, a5 = 0;
        #pragma unroll 4
        for (int r = 0; r < 218; ++r) {
            const float xv = xs[r];
            const float* row = CCX + (size_t)r * RL + t;
            a0 += xv * row[0];
            a1 += xv * row[256];
            a2 += xv * row[512];
            a3 += xv * row[768];
            a4 += xv * row[1024];
            a5 += xv * row[1280];   // t>=88 reads spill into Jreg cols: discarded
        }
        Ml[t] = a0;
        Ml[t + 256] = a1;
        Ml[t + 512] = a2;
        Ml[t + 768] = a3;
        Ml[t + 1024] = a4;
        if (t < 88) Ml[t + 1280] = a5;
    }
    __syncthreads();

    // ---- phase 6: joints ----
    if (t < 57) {
        const int j = t / 3, c = t - (t / 3) * 3;
        float a = 0.f;
        #pragma unroll
        for (int i = 0; i < 24; ++i) {
            const int mb = (j * 24 + i) * 3;
            a += Rg[i][c * 3 + 0] * Ml[mb + 0]
               + Rg[i][c * 3 + 1] * Ml[mb + 1]
               + Rg[i][c * 3 + 2] * Ml[mb + 2]
               + tA[i][c] * CCX[(size_t)218 * RL + mb];   // Wjr
        }
        out[b * 57 + t] = a;
    }
}

extern "C" void kernel_launch(void* const* d_in, const int* in_sizes, int n_in,
                              void* d_out, int out_size, void* d_ws, size_t ws_size,
                              hipStream_t stream) {
    const float* beta  = (const float*)d_in[0];
    const float* theta = (const float*)d_in[1];
    const float* vt    = (const float*)d_in[2];
    const float* sd    = (const float*)d_in[3];
    const float* pd    = (const float*)d_in[4];
    const float* Jreg  = (const float*)d_in[5];
    const float* jr    = (const float*)d_in[6];
    const float* w     = (const float*)d_in[7];
    float* outp = (float*)d_out;
    float* CCX  = (float*)d_ws;

    hipMemsetAsync(CCX, 0, (size_t)NROWS * RL * sizeof(float), stream);
    smpl_pre<<<448, 256, 0, stream>>>(vt, sd, pd, Jreg, jr, w, CCX);
    smpl_batch<<<512, 256, 0, stream>>>(beta, theta, CCX, outp);
}